// Round 3
// baseline (76.673 us; speedup 1.0000x reference)
//
#include <hip/hip_runtime.h>

// Problem constants (match reference)
#define MAX_ATOMS   80
#define MAX_DEGREE  4
#define RING_FLAT   80                        // MAX_RINGS * RING_SIZE
#define EDGE_FLAT   320                       // MAX_ATOMS * MAX_DEGREE
#define MPB         8                         // molecules per block
#define THREADS     (MPB * MAX_ATOMS)         // 640 = 10 waves

typedef float vf4 __attribute__((ext_vector_type(4)));   // native vector for nontemporal builtins

// One thread per atom. Block handles 8 consecutive molecules:
// contiguous 10 KB of edges, 2.5 KB of rings, 10 KB of out per block.
__global__ __launch_bounds__(THREADS) void Find_Ring_Bonds_kernel(
    const float* __restrict__ edges,   // [B, 80, 4] float (int values, -1 = null)
    const int*   __restrict__ rings,   // [B, 10, 8] int  (-1 = pad)
    float*       __restrict__ out,     // [B, 80, 4, 1] float
    int B)
{
    __shared__ unsigned mask[MPB * MAX_ATOMS];

    const int t   = threadIdx.x;
    const int ml  = t / MAX_ATOMS;            // local molecule 0..7
    const int a   = t - ml * MAX_ATOMS;       // atom / ring-slot 0..79
    const int mol = blockIdx.x * MPB + ml;
    const bool live = (mol < B);

    // Phase 0: zero the atom->ringmask table (1 entry per thread)
    mask[t] = 0u;
    __syncthreads();

    // Phase 1: scatter ring membership. Flat ring slot a -> ring (a>>3).
    if (live) {
        int v = rings[(size_t)mol * RING_FLAT + a];
        if (v >= 0) atomicOr(&mask[ml * MAX_ATOMS + v], 1u << (a >> 3));
    }
    __syncthreads();

    // Phase 2: one vf4 edge load + mask lookups + one nontemporal vf4 store
    if (live) {
        const unsigned* __restrict__ m = &mask[ml * MAX_ATOMS];
        const vf4 ev = ((const vf4*)edges)[(size_t)mol * MAX_ATOMS + a];
        const unsigned ma = m[a];

        const int nx = (int)ev.x, ny = (int)ev.y, nz = (int)ev.z, nw = (int)ev.w;
        // clamp -1 -> 0 for a safe LDS read; validity enforced by (n >= 0)
        const unsigned hx = ma & m[nx < 0 ? 0 : nx];
        const unsigned hy = ma & m[ny < 0 ? 0 : ny];
        const unsigned hz = ma & m[nz < 0 ? 0 : nz];
        const unsigned hw = ma & m[nw < 0 ? 0 : nw];

        vf4 r;
        r.x = (nx >= 0 && hx) ? 1.0f : 0.0f;
        r.y = (ny >= 0 && hy) ? 1.0f : 0.0f;
        r.z = (nz >= 0 && hz) ? 1.0f : 0.0f;
        r.w = (nw >= 0 && hw) ? 1.0f : 0.0f;

        // out is write-only and re-poisoned each iter -> bypass cache
        __builtin_nontemporal_store(r, &((vf4*)out)[(size_t)mol * MAX_ATOMS + a]);
    }
}

extern "C" void kernel_launch(void* const* d_in, const int* in_sizes, int n_in,
                              void* d_out, int out_size, void* d_ws, size_t ws_size,
                              hipStream_t stream) {
    const float* edges = (const float*)d_in[0];   // [B,80,4] float32
    const int*   rings = (const int*)d_in[1];     // [B,10,8] int32
    float*       out   = (float*)d_out;           // [B,80,4,1] float32

    const int B = in_sizes[0] / EDGE_FLAT;        // 16384
    const int grid = (B + MPB - 1) / MPB;         // 2048 blocks

    Find_Ring_Bonds_kernel<<<grid, THREADS, 0, stream>>>(edges, rings, out, B);
}